// Round 6
// baseline (1602.598 us; speedup 1.0000x reference)
//
#include <hip/hip_runtime.h>
#include <stdint.h>

typedef unsigned short u16t;
typedef unsigned int   u32t;
typedef unsigned long long u64t;
typedef __attribute__((ext_vector_type(4))) float f32x4;
typedef __attribute__((ext_vector_type(8))) short s16x8;
typedef __attribute__((ext_vector_type(4))) u32t u32x4;

#define NB 4
#define NS 2048
#define ND 1024
#define NH 16
#define NBH 64
#define NTOK 8192
#define TOPK 204
#define KSCALE 184.6649652337873f   /* 1024*log2(e)/8 */

__device__ __forceinline__ u16t f2bf(float f){
  u32t u = __builtin_bit_cast(u32t, f);
  u32t r = (u + 0x7FFFu + ((u >> 16) & 1u)) >> 16;
  return (u16t)r;
}
__device__ __forceinline__ float bf2f(u16t h){
  u32t u = ((u32t)h) << 16;
  return __builtin_bit_cast(float, u);
}
__device__ __forceinline__ f32x4 mfma16(s16x8 a, s16x8 b, f32x4 c){
  return __builtin_amdgcn_mfma_f32_16x16x32_bf16(a, b, c, 0, 0, 0);
}
__device__ __forceinline__ u32t pk_bf16(float a, float b){
  u32t r;
  asm volatile("v_cvt_pk_bf16_f32 %0, %1, %2" : "=v"(r) : "v"(a), "v"(b));
  return r;
}
__device__ __forceinline__ u32t mkkey(float s){
  float kf = fmaf(s, KSCALE, 32768.0f);
  kf = fminf(fmaxf(kf, 0.0f), 65535.0f);
  return (u32t)rintf(kf);
}

#define SWZ(r) (((r) & 7) << 4)

// ---------------- split / convert kernels ----------------
__global__ __launch_bounds__(256) void split_pair_kernel(const float* __restrict__ src,
    u16t* __restrict__ hi, u16t* __restrict__ lo, int n4){
  int i = blockIdx.x * 256 + threadIdx.x;
  if (i >= n4) return;
  float4 v = ((const float4*)src)[i];
  float a0=v.x, a1=v.y, a2=v.z, a3=v.w;
  u16t h0=f2bf(a0), h1=f2bf(a1), h2=f2bf(a2), h3=f2bf(a3);
  u16t l0=f2bf(a0-bf2f(h0)), l1=f2bf(a1-bf2f(h1)), l2=f2bf(a2-bf2f(h2)), l3=f2bf(a3-bf2f(h3));
  ((u64t*)hi)[i] = (u64t)h0 | ((u64t)h1<<16) | ((u64t)h2<<32) | ((u64t)h3<<48);
  ((u64t*)lo)[i] = (u64t)l0 | ((u64t)l1<<16) | ((u64t)l2<<32) | ((u64t)l3<<48);
}

__global__ __launch_bounds__(256) void cvt_kernel(const float* __restrict__ src,
    u16t* __restrict__ dst, int n4){
  int i = blockIdx.x * 256 + threadIdx.x;
  if (i >= n4) return;
  float4 v = ((const float4*)src)[i];
  u16t h0=f2bf(v.x), h1=f2bf(v.y), h2=f2bf(v.z), h3=f2bf(v.w);
  ((u64t*)dst)[i] = (u64t)h0 | ((u64t)h1<<16) | ((u64t)h2<<32) | ((u64t)h3<<48);
}

// ---------------- QKV GEMM: C[8192,3072] = (xh+xl)(Wh+Wl)^T + b, split 3-pass ----------------
__global__ __launch_bounds__(256) void qkv_gemm_kernel(
    const u16t* __restrict__ Ah, const u16t* __restrict__ Al,
    const u16t* __restrict__ Bh, const u16t* __restrict__ Bl,
    const float* __restrict__ bias,
    float* __restrict__ qout, u16t* __restrict__ khi, u16t* __restrict__ klo,
    u16t* __restrict__ vt)
{
  __shared__ u16t lds[4*4096];
  const int tid = threadIdx.x;
  const int l = tid & 63, w = tid >> 6;
  const int wr = w >> 1, wc = w & 1;
  const int mt = blockIdx.y, nt = blockIdx.x;
  f32x4 acc[4][4] = {};
  for (int ks = 0; ks < 32; ++ks){
    __syncthreads();
    #pragma unroll
    for (int p = 0; p < 4; ++p){
      const u16t* src = (p==0) ? Ah : (p==1) ? Al : (p==2) ? Bh : Bl;
      int rb = ((p < 2) ? mt : nt) * 128;
      #pragma unroll
      for (int ii = 0; ii < 2; ++ii){
        int c = tid + ii*256;
        int row = c >> 2, kc = c & 3;
        s16x8 v = *(const s16x8*)(src + (size_t)(rb + row)*1024 + ks*32 + kc*8);
        *(s16x8*)((char*)lds + p*8192 + ((row*64 + kc*16) ^ SWZ(row))) = v;
      }
    }
    __syncthreads();
    s16x8 afh[4], afl[4], bfh[4], bfl[4];
    const int kb = (l >> 4) * 16;
    #pragma unroll
    for (int i = 0; i < 4; ++i){
      int row = wr*64 + i*16 + (l & 15);
      int off = (row*64 + kb) ^ SWZ(row);
      afh[i] = *(const s16x8*)((char*)lds + off);
      afl[i] = *(const s16x8*)((char*)lds + 8192 + off);
    }
    #pragma unroll
    for (int j = 0; j < 4; ++j){
      int row = wc*64 + j*16 + (l & 15);
      int off = (row*64 + kb) ^ SWZ(row);
      bfh[j] = *(const s16x8*)((char*)lds + 16384 + off);
      bfl[j] = *(const s16x8*)((char*)lds + 24576 + off);
    }
    #pragma unroll
    for (int i = 0; i < 4; ++i)
      #pragma unroll
      for (int j = 0; j < 4; ++j){
        acc[i][j] = mfma16(afh[i], bfh[j], acc[i][j]);
        acc[i][j] = mfma16(afh[i], bfl[j], acc[i][j]);
        acc[i][j] = mfma16(afl[i], bfh[j], acc[i][j]);
      }
  }
  #pragma unroll
  for (int j = 0; j < 4; ++j){
    int col = nt*128 + wc*64 + j*16 + (l & 15);
    float bv = bias[col];
    #pragma unroll
    for (int i = 0; i < 4; ++i){
      int tok0 = mt*128 + wr*64 + i*16 + (l >> 4)*4;
      int b = tok0 >> 11;
      int s0 = tok0 & 2047;
      if (col < 1024){
        int h = col >> 6, d = col & 63;
        float* dst = qout + ((size_t)(b*NH + h)*NS + s0)*64 + d;
        #pragma unroll
        for (int r = 0; r < 4; ++r) dst[(size_t)r*64] = acc[i][j][r] + bv;
      } else if (col < 2048){
        int ch = col - 1024; int h = ch >> 6, d = ch & 63;
        size_t idx = ((size_t)(b*NH + h)*NS + s0)*64 + d;
        #pragma unroll
        for (int r = 0; r < 4; ++r){
          float v0 = acc[i][j][r] + bv;
          u16t hh = f2bf(v0);
          khi[idx + (size_t)r*64] = hh;
          klo[idx + (size_t)r*64] = f2bf(v0 - bf2f(hh));
        }
      } else {
        int ch = col - 2048; int h = ch >> 6, d = ch & 63;
        u32t p0 = (u32t)f2bf(acc[i][j][0] + bv) | ((u32t)f2bf(acc[i][j][1] + bv) << 16);
        u32t p1 = (u32t)f2bf(acc[i][j][2] + bv) | ((u32t)f2bf(acc[i][j][3] + bv) << 16);
        u64t pk = (u64t)p0 | ((u64t)p1 << 32);
        *(u64t*)(vt + ((size_t)(b*NH + h)*64 + d)*NS + s0) = pk;
      }
    }
  }
}

// ---------------- out GEMM ----------------
__global__ __launch_bounds__(256) void out_gemm_kernel(
    const u16t* __restrict__ A, const u16t* __restrict__ Bt,
    const float* __restrict__ bias, float* __restrict__ Y)
{
  __shared__ u16t lds[2*4096];
  const int tid = threadIdx.x;
  const int l = tid & 63, w = tid >> 6;
  const int wr = w >> 1, wc = w & 1;
  const int mt = blockIdx.y, nt = blockIdx.x;
  f32x4 acc[4][4] = {};
  for (int ks = 0; ks < 32; ++ks){
    __syncthreads();
    #pragma unroll
    for (int p = 0; p < 2; ++p){
      const u16t* src = p ? Bt : A;
      int rb = (p ? nt : mt) * 128;
      #pragma unroll
      for (int ii = 0; ii < 2; ++ii){
        int c = tid + ii*256;
        int row = c >> 2, kc = c & 3;
        s16x8 v = *(const s16x8*)(src + (size_t)(rb + row)*1024 + ks*32 + kc*8);
        *(s16x8*)((char*)lds + p*8192 + ((row*64 + kc*16) ^ SWZ(row))) = v;
      }
    }
    __syncthreads();
    s16x8 af[4], bf[4];
    const int kb = (l >> 4) * 16;
    #pragma unroll
    for (int i = 0; i < 4; ++i){
      int row = wr*64 + i*16 + (l & 15);
      af[i] = *(const s16x8*)((char*)lds + ((row*64 + kb) ^ SWZ(row)));
    }
    #pragma unroll
    for (int j = 0; j < 4; ++j){
      int row = wc*64 + j*16 + (l & 15);
      bf[j] = *(const s16x8*)((char*)lds + 8192 + ((row*64 + kb) ^ SWZ(row)));
    }
    #pragma unroll
    for (int i = 0; i < 4; ++i)
      #pragma unroll
      for (int j = 0; j < 4; ++j)
        acc[i][j] = mfma16(af[i], bf[j], acc[i][j]);
  }
  #pragma unroll
  for (int j = 0; j < 4; ++j){
    int col = nt*128 + wc*64 + j*16 + (l & 15);
    float bv = bias[col];
    #pragma unroll
    for (int i = 0; i < 4; ++i){
      int tok0 = mt*128 + wr*64 + i*16 + (l >> 4)*4;
      float* dst = Y + (size_t)tok0*1024 + col;
      #pragma unroll
      for (int r = 0; r < 4; ++r) dst[(size_t)r*1024] = acc[i][j][r] + bv;
    }
  }
}

// ---------------- fused sparse attention: 1 WG = (bh, 8 q-rows), 32KB LDS, 4-5 blocks/CU ----
// R4 structure verbatim; MFMA cols 8-15 duplicate cols 0-7 and are discarded.
__global__ __launch_bounds__(256, 4) void attn_fused_kernel(
    const float* __restrict__ qbuf, const u16t* __restrict__ khi,
    const u16t* __restrict__ klo, const u16t* __restrict__ vtg,
    u16t* __restrict__ aout)
{
  __shared__ char smem[32768];   // [8][2048] u16 keys -> bf16 weights, swizzled
  const int tid = threadIdx.x;
  const int l = tid & 63, w = tid >> 6;
  int lid = ((blockIdx.x & 7) << 11) | (blockIdx.x >> 3); // XCD-chunked swizzle (16384%8==0)
  const int bh = lid >> 8, qt = lid & 255;
  const int qrow = l & 15;
  const int qr8 = qrow & 7;            // valid q-row (cols 8-15 duplicate 0-7)
  const size_t kbase = (size_t)bh*NS*64 + (l >> 4)*8;

  // Phase 0: Q fragments (B operand): col = qrow, row source clamped to qr8
  s16x8 qh[2], ql[2];
  {
    const float* qp = qbuf + ((size_t)bh*NS + qt*8 + qr8)*64 + (l >> 4)*8;
    #pragma unroll
    for (int c = 0; c < 2; ++c){
      float4 va = *(const float4*)(qp + c*32);
      float4 vb = *(const float4*)(qp + c*32 + 4);
      float vv[8] = {va.x,va.y,va.z,va.w,vb.x,vb.y,vb.z,vb.w};
      #pragma unroll
      for (int e = 0; e < 8; ++e){
        u16t hh = f2bf(vv[e]);
        qh[c][e] = (short)hh;
        ql[c][e] = (short)f2bf(vv[e] - bf2f(hh));
      }
    }
  }

  // Phase 1: keys. Wave w handles toks g*64 + w*16 .. +15 for g = 0..31.  [R4 verbatim]
  s16x8 nh0, nh1, nl0, nl1;
  {
    size_t a = kbase + (size_t)(w*16 + qrow)*64;
    nh0 = *(const s16x8*)(khi + a);
    nh1 = *(const s16x8*)(khi + a + 32);
    nl0 = *(const s16x8*)(klo + a);
    nl1 = *(const s16x8*)(klo + a + 32);
  }
  for (int g = 0; g < 32; ++g){
    s16x8 h0 = nh0, h1 = nh1, g0 = nl0, g1 = nl1;
    if (g + 1 < 32){
      size_t a = kbase + (size_t)((g+1)*64 + w*16 + qrow)*64;
      nh0 = *(const s16x8*)(khi + a);
      nh1 = *(const s16x8*)(khi + a + 32);
      nl0 = *(const s16x8*)(klo + a);
      nl1 = *(const s16x8*)(klo + a + 32);
    }
    f32x4 acc = {};
    acc = mfma16(h0, qh[0], acc);
    acc = mfma16(h1, qh[1], acc);
    acc = mfma16(h0, ql[0], acc);
    acc = mfma16(h1, ql[1], acc);
    acc = mfma16(g0, qh[0], acc);
    acc = mfma16(g1, qh[1], acc);
    int t0 = g*64 + w*16 + (l >> 4)*4;
    u32t k0 = mkkey(acc[0]), k1 = mkkey(acc[1]);
    u32t k2 = mkkey(acc[2]), k3 = mkkey(acc[3]);
    u64t pk = (u64t)(k0 | (k1 << 16)) | ((u64t)(k2 | (k3 << 16)) << 32);
    if (qrow < 8)
      *(u64t*)(smem + ((qrow*4096 + t0*2) ^ SWZ(qrow))) = pk;
  }
  __syncthreads();

  // Phase 2: rows w*2..w*2+1; exact threshold + weights (in-place)  [R4 body verbatim]
  for (int rr = 0; rr < 2; ++rr){
    int row = w*2 + rr;
    int rb = row*4096, rs = SWZ(row);
    u32t ku[16], kl[16];
    #pragma unroll
    for (int i = 0; i < 4; ++i){
      u32x4 v = *(const u32x4*)(smem + ((rb + i*1024 + l*16) ^ rs));
      #pragma unroll
      for (int j = 0; j < 4; ++j){ ku[i*4+j] = v[j]; kl[i*4+j] = v[j] << 16; }
    }
    // row max key
    u32t mh = 0, ml = 0;
    #pragma unroll
    for (int i = 0; i < 16; ++i){
      mh = mh > ku[i] ? mh : ku[i];
      ml = ml > kl[i] ? ml : kl[i];
    }
    u32t km = mh >> 16, m2 = ml >> 16;
    km = km > m2 ? km : m2;
    #pragma unroll
    for (int o = 32; o; o >>= 1){
      u32t t = (u32t)__shfl_xor((int)km, o);
      km = km > t ? km : t;
    }

    #define CNTLT(mid, out) {                                   \
      u32t mm = (mid) << 16;                                    \
      u32t c0=0,c1=0,c2=0,c3=0;                                 \
      _Pragma("unroll")                                         \
      for (int i = 0; i < 16; i += 4){                          \
        c0 += (ku[i  ] < mm) + (kl[i  ] < mm);                  \
        c1 += (ku[i+1] < mm) + (kl[i+1] < mm);                  \
        c2 += (ku[i+2] < mm) + (kl[i+2] < mm);                  \
        c3 += (ku[i+3] < mm) + (kl[i+3] < mm);                  \
      }                                                         \
      u32t cc = (c0+c1)+(c2+c3);                                \
      _Pragma("unroll")                                         \
      for (int o = 32; o; o >>= 1) cc += (u32t)__shfl_xor((int)cc, o); \
      out = cc;                                                 \
    }

    u32t lo, hi, cseed;
    CNTLT(32768u, cseed);
    if (2048u - cseed >= (u32t)TOPK){ lo = 32768u; hi = km; }
    else                            { lo = 0u;     hi = 32767u; }
    while (lo < hi){
      u32t mid = (lo + hi + 1u) >> 1;
      u32t c; CNTLT(mid, c);
      if (2048u - c >= (u32t)TOPK) lo = mid; else hi = mid - 1u;
    }
    const u32t kbt = lo;
    #undef CNTLT

    const u32t kmxe = km < 32768u ? 32768u : km;
    const float dsh = -(float)kmxe * 0.0009765625f;
    const float em = exp2f(fmaf(32768.0f, 0.0009765625f, dsh));
    float wv[32];
    float zs = 0.0f;
    #pragma unroll
    for (int i = 0; i < 16; ++i){
      u32t x0 = ku[i] & 0xFFFFu, x1 = ku[i] >> 16;
      float e0 = exp2f(fmaf((float)x0, 0.0009765625f, dsh));
      float e1 = exp2f(fmaf((float)x1, 0.0009765625f, dsh));
      wv[2*i]   = (x0 >= kbt) ? e0 : em;
      wv[2*i+1] = (x1 >= kbt) ? e1 : em;
      zs += wv[2*i] + wv[2*i+1];
    }
    #pragma unroll
    for (int o = 32; o; o >>= 1) zs += __shfl_xor(zs, o);
    const float zinv = 1.0f / (zs + 1e-9f);
    #pragma unroll
    for (int i = 0; i < 4; ++i){
      u32x4 o;
      #pragma unroll
      for (int j = 0; j < 4; ++j){
        int e = 2*(i*4+j);
        o[j] = pk_bf16(wv[e]*zinv, wv[e+1]*zinv);
      }
      *(u32x4*)(smem + ((rb + i*1024 + l*16) ^ rs)) = o;
    }
  }
  __syncthreads();

  // Phase 3: PV via mfma(V^T, W): C[d][qrow]. Wave w owns d-block w*16..+15.  [R4 verbatim]
  // B (weights) row clamped to l&7; cols 8-15 duplicate and are discarded.
  f32x4 pacc = {};
  const int lr = l & 7;
  const u16t* vp = vtg + ((size_t)bh*64 + w*16 + qrow)*NS + (l >> 4)*8;
  s16x8 nv0 = *(const s16x8*)(vp);
  s16x8 nv1 = *(const s16x8*)(vp + 32);
  for (int kt = 0; kt < 32; ++kt){
    s16x8 v0 = nv0, v1 = nv1;
    if (kt + 1 < 32){
      nv0 = *(const s16x8*)(vp + (kt+1)*64);
      nv1 = *(const s16x8*)(vp + (kt+1)*64 + 32);
    }
    int tb = (kt*64 + (l >> 4)*8)*2;
    s16x8 w0 = *(const s16x8*)(smem + ((lr*4096 + tb) ^ SWZ(lr)));
    s16x8 w1 = *(const s16x8*)(smem + ((lr*4096 + tb + 64) ^ SWZ(lr)));
    pacc = mfma16(v0, w0, pacc);
    pacc = mfma16(v1, w1, pacc);
  }
  // epilogue: lane holds C[d][qrow]; only cols 0-7 are real q-rows
  if (qrow < 8){
    int tok = qt*8 + qrow;
    int b = bh >> 4, h = bh & 15;
    int d0 = w*16 + (l >> 4)*4;
    u32t p0 = pk_bf16(pacc[0], pacc[1]);
    u32t p1 = pk_bf16(pacc[2], pacc[3]);
    *(u64t*)(aout + ((size_t)(b*NS + tok))*1024 + h*64 + d0) = (u64t)p0 | ((u64t)p1 << 32);
  }
}

// ---------------- workspace layout (132.1 MB, proven available) ----------------
#define O_XHI  ((size_t)0)
#define O_XLO  (O_XHI + (size_t)NTOK*ND*2)
#define O_WQH  (O_XLO + (size_t)NTOK*ND*2)
#define O_WQL  (O_WQH + (size_t)3072*1024*2)
#define O_WOB  (O_WQL + (size_t)3072*1024*2)
#define O_Q    (O_WOB + (size_t)1024*1024*2)
#define O_KHI  (O_Q   + (size_t)NBH*NS*64*4)
#define O_KLO  (O_KHI + (size_t)NBH*NS*64*2)
#define O_VT   (O_KLO + (size_t)NBH*NS*64*2)
#define O_AOUT O_XHI   /* alias: x_hi dead after QKV GEMM */
#define WS_NEED (O_VT + (size_t)NBH*NS*64*2)

extern "C" void kernel_launch(void* const* d_in, const int* in_sizes, int n_in,
                              void* d_out, int out_size, void* d_ws, size_t ws_size,
                              hipStream_t stream)
{
  (void)in_sizes; (void)n_in; (void)out_size;
  const float* x    = (const float*)d_in[0];
  const float* Wqkv = (const float*)d_in[1];
  const float* bqkv = (const float*)d_in[2];
  const float* Wo   = (const float*)d_in[3];
  const float* bo   = (const float*)d_in[4];
  float* Y = (float*)d_out;
  char* ws = (char*)d_ws;
  if (ws_size < WS_NEED) return;

  u16t* xhi  = (u16t*)(ws + O_XHI);
  u16t* xlo  = (u16t*)(ws + O_XLO);
  u16t* wqh  = (u16t*)(ws + O_WQH);
  u16t* wql  = (u16t*)(ws + O_WQL);
  u16t* wob  = (u16t*)(ws + O_WOB);
  float* qbuf = (float*)(ws + O_Q);
  u16t* khi  = (u16t*)(ws + O_KHI);
  u16t* klo  = (u16t*)(ws + O_KLO);
  u16t* vt   = (u16t*)(ws + O_VT);
  u16t* aout = (u16t*)(ws + O_AOUT);

  split_pair_kernel<<<(NTOK*ND/4)/256, 256, 0, stream>>>(x, xhi, xlo, NTOK*ND/4);
  split_pair_kernel<<<(3072*1024/4)/256, 256, 0, stream>>>(Wqkv, wqh, wql, 3072*1024/4);
  cvt_kernel<<<(1024*1024/4)/256, 256, 0, stream>>>(Wo, wob, 1024*1024/4);
  qkv_gemm_kernel<<<dim3(24, 64), 256, 0, stream>>>(xhi, xlo, wqh, wql, bqkv,
                                                    qbuf, khi, klo, vt);
  attn_fused_kernel<<<16384, 256, 0, stream>>>(qbuf, khi, klo, vt, aout);
  out_gemm_kernel<<<dim3(8, 64), 256, 0, stream>>>(aout, wob, bo, Y);
}

// Round 7
// 1251.380 us; speedup vs baseline: 1.2807x; 1.2807x over previous
//
#include <hip/hip_runtime.h>
#include <stdint.h>

typedef unsigned short u16t;
typedef unsigned int   u32t;
typedef unsigned long long u64t;
typedef __attribute__((ext_vector_type(4))) float f32x4;
typedef __attribute__((ext_vector_type(8))) short s16x8;
typedef __attribute__((ext_vector_type(4))) u32t u32x4;

#define NB 4
#define NS 2048
#define ND 1024
#define NH 16
#define NBH 64
#define NTOK 8192
#define TOPK 204
#define KSCALE 184.6649652337873f   /* 1024*log2(e)/8 */

__device__ __forceinline__ u16t f2bf(float f){
  u32t u = __builtin_bit_cast(u32t, f);
  u32t r = (u + 0x7FFFu + ((u >> 16) & 1u)) >> 16;
  return (u16t)r;
}
__device__ __forceinline__ float bf2f(u16t h){
  u32t u = ((u32t)h) << 16;
  return __builtin_bit_cast(float, u);
}
__device__ __forceinline__ f32x4 mfma16(s16x8 a, s16x8 b, f32x4 c){
  return __builtin_amdgcn_mfma_f32_16x16x32_bf16(a, b, c, 0, 0, 0);
}
__device__ __forceinline__ u32t pk_bf16(float a, float b){
  u32t r;
  asm volatile("v_cvt_pk_bf16_f32 %0, %1, %2" : "=v"(r) : "v"(a), "v"(b));
  return r;
}
__device__ __forceinline__ u32t mkkey(float s){
  float kf = fmaf(s, KSCALE, 32768.0f);
  kf = fminf(fmaxf(kf, 0.0f), 65535.0f);
  return (u32t)rintf(kf);
}
__device__ __forceinline__ u64t sxor64(u64t v, int o){
  u32t lo = (u32t)v, hi = (u32t)(v >> 32);
  lo = (u32t)__shfl_xor((int)lo, o);
  hi = (u32t)__shfl_xor((int)hi, o);
  return (u64t)lo | ((u64t)hi << 32);
}

#define SWZ(r) (((r) & 7) << 4)

// ---------------- split / convert kernels ----------------
__global__ __launch_bounds__(256) void split_pair_kernel(const float* __restrict__ src,
    u16t* __restrict__ hi, u16t* __restrict__ lo, int n4){
  int i = blockIdx.x * 256 + threadIdx.x;
  if (i >= n4) return;
  float4 v = ((const float4*)src)[i];
  float a0=v.x, a1=v.y, a2=v.z, a3=v.w;
  u16t h0=f2bf(a0), h1=f2bf(a1), h2=f2bf(a2), h3=f2bf(a3);
  u16t l0=f2bf(a0-bf2f(h0)), l1=f2bf(a1-bf2f(h1)), l2=f2bf(a2-bf2f(h2)), l3=f2bf(a3-bf2f(h3));
  ((u64t*)hi)[i] = (u64t)h0 | ((u64t)h1<<16) | ((u64t)h2<<32) | ((u64t)h3<<48);
  ((u64t*)lo)[i] = (u64t)l0 | ((u64t)l1<<16) | ((u64t)l2<<32) | ((u64t)l3<<48);
}

__global__ __launch_bounds__(256) void cvt_kernel(const float* __restrict__ src,
    u16t* __restrict__ dst, int n4){
  int i = blockIdx.x * 256 + threadIdx.x;
  if (i >= n4) return;
  float4 v = ((const float4*)src)[i];
  u16t h0=f2bf(v.x), h1=f2bf(v.y), h2=f2bf(v.z), h3=f2bf(v.w);
  ((u64t*)dst)[i] = (u64t)h0 | ((u64t)h1<<16) | ((u64t)h2<<32) | ((u64t)h3<<48);
}

// ---------------- QKV GEMM: C[8192,3072] = (xh+xl)(Wh+Wl)^T + b, split 3-pass ----------------
__global__ __launch_bounds__(256) void qkv_gemm_kernel(
    const u16t* __restrict__ Ah, const u16t* __restrict__ Al,
    const u16t* __restrict__ Bh, const u16t* __restrict__ Bl,
    const float* __restrict__ bias,
    float* __restrict__ qout, u16t* __restrict__ khi, u16t* __restrict__ klo,
    u16t* __restrict__ vt)
{
  __shared__ u16t lds[4*4096];
  const int tid = threadIdx.x;
  const int l = tid & 63, w = tid >> 6;
  const int wr = w >> 1, wc = w & 1;
  const int mt = blockIdx.y, nt = blockIdx.x;
  f32x4 acc[4][4] = {};
  for (int ks = 0; ks < 32; ++ks){
    __syncthreads();
    #pragma unroll
    for (int p = 0; p < 4; ++p){
      const u16t* src = (p==0) ? Ah : (p==1) ? Al : (p==2) ? Bh : Bl;
      int rb = ((p < 2) ? mt : nt) * 128;
      #pragma unroll
      for (int ii = 0; ii < 2; ++ii){
        int c = tid + ii*256;
        int row = c >> 2, kc = c & 3;
        s16x8 v = *(const s16x8*)(src + (size_t)(rb + row)*1024 + ks*32 + kc*8);
        *(s16x8*)((char*)lds + p*8192 + ((row*64 + kc*16) ^ SWZ(row))) = v;
      }
    }
    __syncthreads();
    s16x8 afh[4], afl[4], bfh[4], bfl[4];
    const int kb = (l >> 4) * 16;
    #pragma unroll
    for (int i = 0; i < 4; ++i){
      int row = wr*64 + i*16 + (l & 15);
      int off = (row*64 + kb) ^ SWZ(row);
      afh[i] = *(const s16x8*)((char*)lds + off);
      afl[i] = *(const s16x8*)((char*)lds + 8192 + off);
    }
    #pragma unroll
    for (int j = 0; j < 4; ++j){
      int row = wc*64 + j*16 + (l & 15);
      int off = (row*64 + kb) ^ SWZ(row);
      bfh[j] = *(const s16x8*)((char*)lds + 16384 + off);
      bfl[j] = *(const s16x8*)((char*)lds + 24576 + off);
    }
    #pragma unroll
    for (int i = 0; i < 4; ++i)
      #pragma unroll
      for (int j = 0; j < 4; ++j){
        acc[i][j] = mfma16(afh[i], bfh[j], acc[i][j]);
        acc[i][j] = mfma16(afh[i], bfl[j], acc[i][j]);
        acc[i][j] = mfma16(afl[i], bfh[j], acc[i][j]);
      }
  }
  #pragma unroll
  for (int j = 0; j < 4; ++j){
    int col = nt*128 + wc*64 + j*16 + (l & 15);
    float bv = bias[col];
    #pragma unroll
    for (int i = 0; i < 4; ++i){
      int tok0 = mt*128 + wr*64 + i*16 + (l >> 4)*4;
      int b = tok0 >> 11;
      int s0 = tok0 & 2047;
      if (col < 1024){
        int h = col >> 6, d = col & 63;
        float* dst = qout + ((size_t)(b*NH + h)*NS + s0)*64 + d;
        #pragma unroll
        for (int r = 0; r < 4; ++r) dst[(size_t)r*64] = acc[i][j][r] + bv;
      } else if (col < 2048){
        int ch = col - 1024; int h = ch >> 6, d = ch & 63;
        size_t idx = ((size_t)(b*NH + h)*NS + s0)*64 + d;
        #pragma unroll
        for (int r = 0; r < 4; ++r){
          float v0 = acc[i][j][r] + bv;
          u16t hh = f2bf(v0);
          khi[idx + (size_t)r*64] = hh;
          klo[idx + (size_t)r*64] = f2bf(v0 - bf2f(hh));
        }
      } else {
        int ch = col - 2048; int h = ch >> 6, d = ch & 63;
        u32t p0 = (u32t)f2bf(acc[i][j][0] + bv) | ((u32t)f2bf(acc[i][j][1] + bv) << 16);
        u32t p1 = (u32t)f2bf(acc[i][j][2] + bv) | ((u32t)f2bf(acc[i][j][3] + bv) << 16);
        u64t pk = (u64t)p0 | ((u64t)p1 << 32);
        *(u64t*)(vt + ((size_t)(b*NH + h)*64 + d)*NS + s0) = pk;
      }
    }
  }
}

// ---------------- out GEMM ----------------
__global__ __launch_bounds__(256) void out_gemm_kernel(
    const u16t* __restrict__ A, const u16t* __restrict__ Bt,
    const float* __restrict__ bias, float* __restrict__ Y)
{
  __shared__ u16t lds[2*4096];
  const int tid = threadIdx.x;
  const int l = tid & 63, w = tid >> 6;
  const int wr = w >> 1, wc = w & 1;
  const int mt = blockIdx.y, nt = blockIdx.x;
  f32x4 acc[4][4] = {};
  for (int ks = 0; ks < 32; ++ks){
    __syncthreads();
    #pragma unroll
    for (int p = 0; p < 2; ++p){
      const u16t* src = p ? Bt : A;
      int rb = (p ? nt : mt) * 128;
      #pragma unroll
      for (int ii = 0; ii < 2; ++ii){
        int c = tid + ii*256;
        int row = c >> 2, kc = c & 3;
        s16x8 v = *(const s16x8*)(src + (size_t)(rb + row)*1024 + ks*32 + kc*8);
        *(s16x8*)((char*)lds + p*8192 + ((row*64 + kc*16) ^ SWZ(row))) = v;
      }
    }
    __syncthreads();
    s16x8 af[4], bf[4];
    const int kb = (l >> 4) * 16;
    #pragma unroll
    for (int i = 0; i < 4; ++i){
      int row = wr*64 + i*16 + (l & 15);
      af[i] = *(const s16x8*)((char*)lds + ((row*64 + kb) ^ SWZ(row)));
    }
    #pragma unroll
    for (int j = 0; j < 4; ++j){
      int row = wc*64 + j*16 + (l & 15);
      bf[j] = *(const s16x8*)((char*)lds + 8192 + ((row*64 + kb) ^ SWZ(row)));
    }
    #pragma unroll
    for (int i = 0; i < 4; ++i)
      #pragma unroll
      for (int j = 0; j < 4; ++j)
        acc[i][j] = mfma16(af[i], bf[j], acc[i][j]);
  }
  #pragma unroll
  for (int j = 0; j < 4; ++j){
    int col = nt*128 + wc*64 + j*16 + (l & 15);
    float bv = bias[col];
    #pragma unroll
    for (int i = 0; i < 4; ++i){
      int tok0 = mt*128 + wr*64 + i*16 + (l >> 4)*4;
      float* dst = Y + (size_t)tok0*1024 + col;
      #pragma unroll
      for (int r = 0; r < 4; ++r) dst[(size_t)r*1024] = acc[i][j][r] + bv;
    }
  }
}

// widen 2x u64 8-bit-field hists into 4x u64 16-bit-field and wave-reduce
#define REDUCE16(h0, h1, e0, e1, e2, e3) {                                  \
  const u64t M8 = 0x00FF00FF00FF00FFull;                                    \
  e0 = (h0) & M8; e1 = ((h0) >> 8) & M8;                                    \
  e2 = (h1) & M8; e3 = ((h1) >> 8) & M8;                                    \
  _Pragma("unroll")                                                         \
  for (int o = 32; o; o >>= 1){                                             \
    e0 += sxor64(e0, o); e1 += sxor64(e1, o);                               \
    e2 += sxor64(e2, o); e3 += sxor64(e3, o);                               \
  } }

// scan 16 bins (ascending) for first cumulative >= t; B = bin, t -> rank in bin
#define SCAN16(e0, e1, e2, e3, t, B) {                                      \
  u32t cum = 0; int fnd = 0; u32t tn = (t);                                 \
  _Pragma("unroll")                                                         \
  for (int b = 0; b < 16; ++b){                                             \
    u64t src = (b < 8) ? ((b & 1) ? (e1) : (e0)) : ((b & 1) ? (e3) : (e2)); \
    u32t c = (u32t)(src >> (((b & 7) >> 1) * 16)) & 0xFFFFu;                \
    if (!fnd && cum + c >= (t)){ (B) = b; tn = (t) - cum; fnd = 1; }        \
    cum += c;                                                               \
  } (t) = tn; }

// ---------------- fused sparse attention: 1 WG = (bh, 16 q-rows), 2 blocks/CU ----------------
// Phase 1: u16 exp-keys via mfma(K,Q) dual-chain, K hi/lo direct from global (prefetched)
// Phase 2: exact 204th-largest key via 3-level packed histogram (fallback: binary search);
//          unnormalized exp2 weights -> LDS; zinv per row -> LDS
// Phase 3: PV via mfma(V^T, W) dual-acc, epilogue scales by zinv
__global__ __launch_bounds__(256) void attn_fused_kernel(
    const float* __restrict__ qbuf, const u16t* __restrict__ khi,
    const u16t* __restrict__ klo, const u16t* __restrict__ vtg,
    u16t* __restrict__ aout)
{
  extern __shared__ char smem[];   // 65536 keys/weights + 64 zinv
  float* zlds = (float*)(smem + 65536);
  const int tid = threadIdx.x;
  const int l = tid & 63, w = tid >> 6;
  int lid = ((blockIdx.x & 7) << 10) | (blockIdx.x >> 3); // XCD-chunked swizzle (8192%8==0)
  const int bh = lid >> 7, qt = lid & 127;
  const int qrow = l & 15;
  const size_t kbase = (size_t)bh*NS*64 + (l >> 4)*8;

  // Phase 0: Q fragments (B operand): row = qrow, d-slice = c*32 + (l>>4)*8
  s16x8 qh[2], ql[2];
  {
    const float* qp = qbuf + ((size_t)bh*NS + qt*16 + qrow)*64 + (l >> 4)*8;
    #pragma unroll
    for (int c = 0; c < 2; ++c){
      float4 va = *(const float4*)(qp + c*32);
      float4 vb = *(const float4*)(qp + c*32 + 4);
      float vv[8] = {va.x,va.y,va.z,va.w,vb.x,vb.y,vb.z,vb.w};
      #pragma unroll
      for (int e = 0; e < 8; ++e){
        u16t hh = f2bf(vv[e]);
        qh[c][e] = (short)hh;
        ql[c][e] = (short)f2bf(vv[e] - bf2f(hh));
      }
    }
  }

  // Phase 1: keys. Wave w handles toks g*64 + w*16 .. +15 for g = 0..31.
  s16x8 nh0, nh1, nl0, nl1;
  {
    size_t a = kbase + (size_t)(w*16 + qrow)*64;
    nh0 = *(const s16x8*)(khi + a);
    nh1 = *(const s16x8*)(khi + a + 32);
    nl0 = *(const s16x8*)(klo + a);
    nl1 = *(const s16x8*)(klo + a + 32);
  }
  for (int g = 0; g < 32; ++g){
    s16x8 h0 = nh0, h1 = nh1, g0 = nl0, g1 = nl1;
    if (g + 1 < 32){
      size_t a = kbase + (size_t)((g+1)*64 + w*16 + qrow)*64;
      nh0 = *(const s16x8*)(khi + a);
      nh1 = *(const s16x8*)(khi + a + 32);
      nl0 = *(const s16x8*)(klo + a);
      nl1 = *(const s16x8*)(klo + a + 32);
    }
    __builtin_amdgcn_s_setprio(1);
    f32x4 aA = {}, aB = {};
    aA = mfma16(h0, qh[0], aA);
    aB = mfma16(h1, qh[1], aB);
    aA = mfma16(h0, ql[0], aA);
    aB = mfma16(h1, ql[1], aB);
    aA = mfma16(g0, qh[0], aA);
    aB = mfma16(g1, qh[1], aB);
    __builtin_amdgcn_s_setprio(0);
    f32x4 acc = aA + aB;
    int t0 = g*64 + w*16 + (l >> 4)*4;
    u32t k0 = mkkey(acc[0]), k1 = mkkey(acc[1]);
    u32t k2 = mkkey(acc[2]), k3 = mkkey(acc[3]);
    u64t pk = (u64t)(k0 | (k1 << 16)) | ((u64t)(k2 | (k3 << 16)) << 32);
    *(u64t*)(smem + ((qrow*4096 + t0*2) ^ SWZ(qrow))) = pk;
  }
  __syncthreads();

  // Phase 2: rows w*4..w*4+3; exact threshold + unnormalized weights + zinv
  for (int rr = 0; rr < 4; ++rr){
    int row = w*4 + rr;
    int rb = row*4096, rs = SWZ(row);
    u32t ku[16];
    #pragma unroll
    for (int i = 0; i < 4; ++i){
      u32x4 v = *(const u32x4*)(smem + ((rb + i*1024 + l*16) ^ rs));
      #pragma unroll
      for (int j = 0; j < 4; ++j) ku[i*4+j] = v[j];
    }
    // row max key (packed halves)
    u32t mh = 0, ml = 0;
    #pragma unroll
    for (int i = 0; i < 16; ++i){
      mh = mh > ku[i] ? mh : ku[i];
      u32t kls = ku[i] << 16;
      ml = ml > kls ? ml : kls;
    }
    u32t km = mh >> 16, m2 = ml >> 16;
    km = km > m2 ? km : m2;
    #pragma unroll
    for (int o = 32; o; o >>= 1){
      u32t t = (u32t)__shfl_xor((int)km, o);
      km = km > t ? km : t;
    }

    // packed distances from max: both halves <= km so no cross-half borrow
    const u32t kmp = km * 0x00010001u;
    u32t dp[16];
    #pragma unroll
    for (int i = 0; i < 16; ++i) dp[i] = kmp - ku[i];

    // ---- Level 1: 16 bins x 128 wide ----
    u64t h0 = 0, h1 = 0;
    #pragma unroll
    for (int i = 0; i < 16; ++i){
      u32t d0 = dp[i] & 0xFFFFu, d1 = dp[i] >> 16;
      u32t b0 = d0 >> 7; b0 = b0 > 15u ? 15u : b0;
      u32t b1 = d1 >> 7; b1 = b1 > 15u ? 15u : b1;
      u64t i0 = 1ull << ((b0 & 7u) << 3);
      u64t i1 = 1ull << ((b1 & 7u) << 3);
      h0 += (b0 < 8u) ? i0 : 0; h1 += (b0 < 8u) ? 0 : i0;
      h0 += (b1 < 8u) ? i1 : 0; h1 += (b1 < 8u) ? 0 : i1;
    }
    u64t e0, e1, e2, e3;
    REDUCE16(h0, h1, e0, e1, e2, e3);
    u32t t = (u32t)TOPK; int B1 = 0;
    SCAN16(e0, e1, e2, e3, t, B1);

    // ---- Level 2: 16 bins x 8 wide within B1 ----
    const u32t base1 = (u32t)B1 << 7;
    h0 = 0; h1 = 0;
    #pragma unroll
    for (int i = 0; i < 16; ++i){
      u32t d0 = dp[i] & 0xFFFFu, d1 = dp[i] >> 16;
      u32t s0 = (d0 - base1) >> 3;
      u32t s1 = (d1 - base1) >> 3;
      bool i0v, i1v;
      if (B1 == 15){
        i0v = d0 >= base1; i1v = d1 >= base1;
        s0 = s0 > 15u ? 15u : s0; s1 = s1 > 15u ? 15u : s1;
      } else {
        i0v = s0 < 16u; i1v = s1 < 16u;
      }
      u64t j0 = 1ull << ((s0 & 7u) << 3);
      u64t j1 = 1ull << ((s1 & 7u) << 3);
      h0 += (i0v && s0 < 8u) ? j0 : 0; h1 += (i0v && s0 >= 8u) ? j0 : 0;
      h0 += (i1v && s1 < 8u) ? j1 : 0; h1 += (i1v && s1 >= 8u) ? j1 : 0;
    }
    REDUCE16(h0, h1, e0, e1, e2, e3);
    int B2 = 0;
    SCAN16(e0, e1, e2, e3, t, B2);

    u32t kbt;
    if (B1 == 15 && B2 == 15){
      // cold fallback: exact binary search in key space (R4 logic)
      u32t lo = 0, hi = km;
      while (lo < hi){
        u32t mid = (lo + hi + 1u) >> 1;
        u32t mm = mid << 16;
        u32t cc = 0;
        #pragma unroll
        for (int i = 0; i < 16; ++i){
          cc += (ku[i] < mm) ? 1u : 0u;
          cc += ((ku[i] << 16) < mm) ? 1u : 0u;
        }
        #pragma unroll
        for (int o = 32; o; o >>= 1) cc += (u32t)__shfl_xor((int)cc, o);
        if (2048u - cc >= (u32t)TOPK) lo = mid; else hi = mid - 1u;
      }
      kbt = lo;
    } else {
      // ---- Level 3: 8 exact values within (B1,B2) ----
      const u32t base2 = base1 + ((u32t)B2 << 3);
      const u32t bb2 = base2 >> 3;
      u64t g0 = 0, g1 = 0;
      #pragma unroll
      for (int i = 0; i < 16; ++i){
        u32t d0 = dp[i] & 0xFFFFu, d1 = dp[i] >> 16;
        u32t v0 = d0 & 7u, v1 = d1 & 7u;
        bool i0v = (d0 >> 3) == bb2;
        bool i1v = (d1 >> 3) == bb2;
        u64t k0 = 1ull << ((v0 & 3u) << 4);
        u64t k1 = 1ull << ((v1 & 3u) << 4);
        g0 += (i0v && v0 < 4u) ? k0 : 0; g1 += (i0v && v0 >= 4u) ? k0 : 0;
        g0 += (i1v && v1 < 4u) ? k1 : 0; g1 += (i1v && v1 >= 4u) ? k1 : 0;
      }
      #pragma unroll
      for (int o = 32; o; o >>= 1){ g0 += sxor64(g0, o); g1 += sxor64(g1, o); }
      u32t cum = 0; int fnd = 0; int B3 = 0;
      #pragma unroll
      for (int v = 0; v < 8; ++v){
        u64t src = (v < 4) ? g0 : g1;
        u32t c = (u32t)(src >> ((v & 3) * 16)) & 0xFFFFu;
        if (!fnd && cum + c >= t){ B3 = v; fnd = 1; }
        cum += c;
      }
      kbt = km - (base2 + (u32t)B3);
    }

    // weights: kept -> 2^((k-kmx)/1024); masked -> em; UNNORMALIZED; zinv -> LDS
    const u32t kmxe = km < 32768u ? 32768u : km;
    const float dsh = -(float)kmxe * 0.0009765625f;
    const float em = exp2f(fmaf(32768.0f, 0.0009765625f, dsh));
    float zs = 0.0f;
    #pragma unroll
    for (int i = 0; i < 4; ++i){
      u32x4 o;
      #pragma unroll
      for (int j = 0; j < 4; ++j){
        u32t kk = ku[i*4+j];
        u32t x0 = kk & 0xFFFFu, x1 = kk >> 16;
        float ea = exp2f(fmaf((float)x0, 0.0009765625f, dsh));
        float eb = exp2f(fmaf((float)x1, 0.0009765625f, dsh));
        float w0 = (x0 >= kbt) ? ea : em;
        float w1 = (x1 >= kbt) ? eb : em;
        zs += w0 + w1;
        o[j] = pk_bf16(w0, w1);
      }
      *(u32x4*)(smem + ((rb + i*1024 + l*16) ^ rs)) = o;
    }
    #pragma unroll
    for (int o = 32; o; o >>= 1) zs += __shfl_xor(zs, o);
    if (l == 0) zlds[row] = 1.0f / (zs + 1e-9f);
  }
  __syncthreads();

  // Phase 3: PV via mfma(V^T, W): C[d][qrow]. Wave w owns d-block w*16..+15.
  f32x4 pA = {}, pB = {};
  const u16t* vp = vtg + ((size_t)bh*64 + w*16 + qrow)*NS + (l >> 4)*8;
  s16x8 nv0 = *(const s16x8*)(vp);
  s16x8 nv1 = *(const s16x8*)(vp + 32);
  for (int kt = 0; kt < 32; ++kt){
    s16x8 v0 = nv0, v1 = nv1;
    if (kt + 1 < 32){
      nv0 = *(const s16x8*)(vp + (kt+1)*64);
      nv1 = *(const s16x8*)(vp + (kt+1)*64 + 32);
    }
    int tb = (kt*64 + (l >> 4)*8)*2;
    s16x8 w0 = *(const s16x8*)(smem + ((qrow*4096 + tb) ^ SWZ(qrow)));
    s16x8 w1 = *(const s16x8*)(smem + ((qrow*4096 + tb + 64) ^ SWZ(qrow)));
    __builtin_amdgcn_s_setprio(1);
    pA = mfma16(v0, w0, pA);
    pB = mfma16(v1, w1, pB);
    __builtin_amdgcn_s_setprio(0);
  }
  f32x4 pacc = pA + pB;
  // epilogue: scale by zinv, store bf16 [B][S][H*64]
  {
    float zi = zlds[qrow];
    int tok = qt*16 + qrow;
    int b = bh >> 4, h = bh & 15;
    int d0 = w*16 + (l >> 4)*4;
    u32t p0 = pk_bf16(pacc[0]*zi, pacc[1]*zi);
    u32t p1 = pk_bf16(pacc[2]*zi, pacc[3]*zi);
    *(u64t*)(aout + ((size_t)(b*NS + tok))*1024 + h*64 + d0) = (u64t)p0 | ((u64t)p1 << 32);
  }
}

// ---------------- workspace layout (132.1 MB, proven available) ----------------
#define O_XHI  ((size_t)0)
#define O_XLO  (O_XHI + (size_t)NTOK*ND*2)
#define O_WQH  (O_XLO + (size_t)NTOK*ND*2)
#define O_WQL  (O_WQH + (size_t)3072*1024*2)
#define O_WOB  (O_WQL + (size_t)3072*1024*2)
#define O_Q    (O_WOB + (size_t)1024*1024*2)
#define O_KHI  (O_Q   + (size_t)NBH*NS*64*4)
#define O_KLO  (O_KHI + (size_t)NBH*NS*64*2)
#define O_VT   (O_KLO + (size_t)NBH*NS*64*2)
#define O_AOUT O_XHI   /* alias: x_hi dead after QKV GEMM */
#define WS_NEED (O_VT + (size_t)NBH*NS*64*2)

#define ATTN_LDS (65536 + 64)

extern "C" void kernel_launch(void* const* d_in, const int* in_sizes, int n_in,
                              void* d_out, int out_size, void* d_ws, size_t ws_size,
                              hipStream_t stream)
{
  (void)in_sizes; (void)n_in; (void)out_size;
  const float* x    = (const float*)d_in[0];
  const float* Wqkv = (const float*)d_in[1];
  const float* bqkv = (const float*)d_in[2];
  const float* Wo   = (const float*)d_in[3];
  const float* bo   = (const float*)d_in[4];
  float* Y = (float*)d_out;
  char* ws = (char*)d_ws;
  if (ws_size < WS_NEED) return;

  u16t* xhi  = (u16t*)(ws + O_XHI);
  u16t* xlo  = (u16t*)(ws + O_XLO);
  u16t* wqh  = (u16t*)(ws + O_WQH);
  u16t* wql  = (u16t*)(ws + O_WQL);
  u16t* wob  = (u16t*)(ws + O_WOB);
  float* qbuf = (float*)(ws + O_Q);
  u16t* khi  = (u16t*)(ws + O_KHI);
  u16t* klo  = (u16t*)(ws + O_KLO);
  u16t* vt   = (u16t*)(ws + O_VT);
  u16t* aout = (u16t*)(ws + O_AOUT);

  hipFuncSetAttribute((const void*)attn_fused_kernel,
                      hipFuncAttributeMaxDynamicSharedMemorySize, ATTN_LDS);

  split_pair_kernel<<<(NTOK*ND/4)/256, 256, 0, stream>>>(x, xhi, xlo, NTOK*ND/4);
  split_pair_kernel<<<(3072*1024/4)/256, 256, 0, stream>>>(Wqkv, wqh, wql, 3072*1024/4);
  cvt_kernel<<<(1024*1024/4)/256, 256, 0, stream>>>(Wo, wob, 1024*1024/4);
  qkv_gemm_kernel<<<dim3(24, 64), 256, 0, stream>>>(xhi, xlo, wqh, wql, bqkv,
                                                    qbuf, khi, klo, vt);
  attn_fused_kernel<<<8192, 256, ATTN_LDS, stream>>>(qbuf, khi, klo, vt, aout);
  out_gemm_kernel<<<dim3(8, 64), 256, 0, stream>>>(aout, wob, bo, Y);
}

// Round 8
// 1085.845 us; speedup vs baseline: 1.4759x; 1.1524x over previous
//
#include <hip/hip_runtime.h>
#include <stdint.h>

typedef unsigned short u16t;
typedef unsigned int   u32t;
typedef unsigned long long u64t;
typedef __attribute__((ext_vector_type(4))) float f32x4;
typedef __attribute__((ext_vector_type(8))) short s16x8;
typedef __attribute__((ext_vector_type(4))) u32t u32x4;

#define NB 4
#define NS 2048
#define ND 1024
#define NH 16
#define NBH 64
#define NTOK 8192
#define TOPK 204
#define KSCALE 184.6649652337873f   /* 1024*log2(e)/8 */

__device__ __forceinline__ u16t f2bf(float f){
  u32t u = __builtin_bit_cast(u32t, f);
  u32t r = (u + 0x7FFFu + ((u >> 16) & 1u)) >> 16;
  return (u16t)r;
}
__device__ __forceinline__ float bf2f(u16t h){
  u32t u = ((u32t)h) << 16;
  return __builtin_bit_cast(float, u);
}
__device__ __forceinline__ f32x4 mfma16(s16x8 a, s16x8 b, f32x4 c){
  return __builtin_amdgcn_mfma_f32_16x16x32_bf16(a, b, c, 0, 0, 0);
}
__device__ __forceinline__ u32t pk_bf16(float a, float b){
  u32t r;
  asm volatile("v_cvt_pk_bf16_f32 %0, %1, %2" : "=v"(r) : "v"(a), "v"(b));
  return r;
}
__device__ __forceinline__ u32t mkkey(float s){
  float kf = fmaf(s, KSCALE, 32768.0f);
  kf = fminf(fmaxf(kf, 0.0f), 65535.0f);
  return (u32t)rintf(kf);
}
__device__ __forceinline__ float exp2_fast(float x){
#if __has_builtin(__builtin_amdgcn_exp2f)
  return __builtin_amdgcn_exp2f(x);
#else
  return exp2f(x);
#endif
}

#define SWZ(r) (((r) & 7) << 4)

// ---------------- split / convert kernels ----------------
__global__ __launch_bounds__(256) void split_pair_kernel(const float* __restrict__ src,
    u16t* __restrict__ hi, u16t* __restrict__ lo, int n4){
  int i = blockIdx.x * 256 + threadIdx.x;
  if (i >= n4) return;
  float4 v = ((const float4*)src)[i];
  float a0=v.x, a1=v.y, a2=v.z, a3=v.w;
  u16t h0=f2bf(a0), h1=f2bf(a1), h2=f2bf(a2), h3=f2bf(a3);
  u16t l0=f2bf(a0-bf2f(h0)), l1=f2bf(a1-bf2f(h1)), l2=f2bf(a2-bf2f(h2)), l3=f2bf(a3-bf2f(h3));
  ((u64t*)hi)[i] = (u64t)h0 | ((u64t)h1<<16) | ((u64t)h2<<32) | ((u64t)h3<<48);
  ((u64t*)lo)[i] = (u64t)l0 | ((u64t)l1<<16) | ((u64t)l2<<32) | ((u64t)l3<<48);
}

__global__ __launch_bounds__(256) void cvt_kernel(const float* __restrict__ src,
    u16t* __restrict__ dst, int n4){
  int i = blockIdx.x * 256 + threadIdx.x;
  if (i >= n4) return;
  float4 v = ((const float4*)src)[i];
  u16t h0=f2bf(v.x), h1=f2bf(v.y), h2=f2bf(v.z), h3=f2bf(v.w);
  ((u64t*)dst)[i] = (u64t)h0 | ((u64t)h1<<16) | ((u64t)h2<<32) | ((u64t)h3<<48);
}

// ---------------- QKV GEMM: C[8192,3072] = (xh+xl)(Wh+Wl)^T + b, split 3-pass ----------------
__global__ __launch_bounds__(256) void qkv_gemm_kernel(
    const u16t* __restrict__ Ah, const u16t* __restrict__ Al,
    const u16t* __restrict__ Bh, const u16t* __restrict__ Bl,
    const float* __restrict__ bias,
    float* __restrict__ qout, u16t* __restrict__ khi, u16t* __restrict__ klo,
    u16t* __restrict__ vt)
{
  __shared__ u16t lds[4*4096];
  const int tid = threadIdx.x;
  const int l = tid & 63, w = tid >> 6;
  const int wr = w >> 1, wc = w & 1;
  const int mt = blockIdx.y, nt = blockIdx.x;
  f32x4 acc[4][4] = {};
  for (int ks = 0; ks < 32; ++ks){
    __syncthreads();
    #pragma unroll
    for (int p = 0; p < 4; ++p){
      const u16t* src = (p==0) ? Ah : (p==1) ? Al : (p==2) ? Bh : Bl;
      int rb = ((p < 2) ? mt : nt) * 128;
      #pragma unroll
      for (int ii = 0; ii < 2; ++ii){
        int c = tid + ii*256;
        int row = c >> 2, kc = c & 3;
        s16x8 v = *(const s16x8*)(src + (size_t)(rb + row)*1024 + ks*32 + kc*8);
        *(s16x8*)((char*)lds + p*8192 + ((row*64 + kc*16) ^ SWZ(row))) = v;
      }
    }
    __syncthreads();
    s16x8 afh[4], afl[4], bfh[4], bfl[4];
    const int kb = (l >> 4) * 16;
    #pragma unroll
    for (int i = 0; i < 4; ++i){
      int row = wr*64 + i*16 + (l & 15);
      int off = (row*64 + kb) ^ SWZ(row);
      afh[i] = *(const s16x8*)((char*)lds + off);
      afl[i] = *(const s16x8*)((char*)lds + 8192 + off);
    }
    #pragma unroll
    for (int j = 0; j < 4; ++j){
      int row = wc*64 + j*16 + (l & 15);
      int off = (row*64 + kb) ^ SWZ(row);
      bfh[j] = *(const s16x8*)((char*)lds + 16384 + off);
      bfl[j] = *(const s16x8*)((char*)lds + 24576 + off);
    }
    #pragma unroll
    for (int i = 0; i < 4; ++i)
      #pragma unroll
      for (int j = 0; j < 4; ++j){
        acc[i][j] = mfma16(afh[i], bfh[j], acc[i][j]);
        acc[i][j] = mfma16(afh[i], bfl[j], acc[i][j]);
        acc[i][j] = mfma16(afl[i], bfh[j], acc[i][j]);
      }
  }
  #pragma unroll
  for (int j = 0; j < 4; ++j){
    int col = nt*128 + wc*64 + j*16 + (l & 15);
    float bv = bias[col];
    #pragma unroll
    for (int i = 0; i < 4; ++i){
      int tok0 = mt*128 + wr*64 + i*16 + (l >> 4)*4;
      int b = tok0 >> 11;
      int s0 = tok0 & 2047;
      if (col < 1024){
        int h = col >> 6, d = col & 63;
        float* dst = qout + ((size_t)(b*NH + h)*NS + s0)*64 + d;
        #pragma unroll
        for (int r = 0; r < 4; ++r) dst[(size_t)r*64] = acc[i][j][r] + bv;
      } else if (col < 2048){
        int ch = col - 1024; int h = ch >> 6, d = ch & 63;
        size_t idx = ((size_t)(b*NH + h)*NS + s0)*64 + d;
        #pragma unroll
        for (int r = 0; r < 4; ++r){
          float v0 = acc[i][j][r] + bv;
          u16t hh = f2bf(v0);
          khi[idx + (size_t)r*64] = hh;
          klo[idx + (size_t)r*64] = f2bf(v0 - bf2f(hh));
        }
      } else {
        int ch = col - 2048; int h = ch >> 6, d = ch & 63;
        u32t p0 = (u32t)f2bf(acc[i][j][0] + bv) | ((u32t)f2bf(acc[i][j][1] + bv) << 16);
        u32t p1 = (u32t)f2bf(acc[i][j][2] + bv) | ((u32t)f2bf(acc[i][j][3] + bv) << 16);
        u64t pk = (u64t)p0 | ((u64t)p1 << 32);
        *(u64t*)(vt + ((size_t)(b*NH + h)*64 + d)*NS + s0) = pk;
      }
    }
  }
}

// ---------------- out GEMM ----------------
__global__ __launch_bounds__(256) void out_gemm_kernel(
    const u16t* __restrict__ A, const u16t* __restrict__ Bt,
    const float* __restrict__ bias, float* __restrict__ Y)
{
  __shared__ u16t lds[2*4096];
  const int tid = threadIdx.x;
  const int l = tid & 63, w = tid >> 6;
  const int wr = w >> 1, wc = w & 1;
  const int mt = blockIdx.y, nt = blockIdx.x;
  f32x4 acc[4][4] = {};
  for (int ks = 0; ks < 32; ++ks){
    __syncthreads();
    #pragma unroll
    for (int p = 0; p < 2; ++p){
      const u16t* src = p ? Bt : A;
      int rb = (p ? nt : mt) * 128;
      #pragma unroll
      for (int ii = 0; ii < 2; ++ii){
        int c = tid + ii*256;
        int row = c >> 2, kc = c & 3;
        s16x8 v = *(const s16x8*)(src + (size_t)(rb + row)*1024 + ks*32 + kc*8);
        *(s16x8*)((char*)lds + p*8192 + ((row*64 + kc*16) ^ SWZ(row))) = v;
      }
    }
    __syncthreads();
    s16x8 af[4], bf[4];
    const int kb = (l >> 4) * 16;
    #pragma unroll
    for (int i = 0; i < 4; ++i){
      int row = wr*64 + i*16 + (l & 15);
      af[i] = *(const s16x8*)((char*)lds + ((row*64 + kb) ^ SWZ(row)));
    }
    #pragma unroll
    for (int j = 0; j < 4; ++j){
      int row = wc*64 + j*16 + (l & 15);
      bf[j] = *(const s16x8*)((char*)lds + 8192 + ((row*64 + kb) ^ SWZ(row)));
    }
    #pragma unroll
    for (int i = 0; i < 4; ++i)
      #pragma unroll
      for (int j = 0; j < 4; ++j)
        acc[i][j] = mfma16(af[i], bf[j], acc[i][j]);
  }
  #pragma unroll
  for (int j = 0; j < 4; ++j){
    int col = nt*128 + wc*64 + j*16 + (l & 15);
    float bv = bias[col];
    #pragma unroll
    for (int i = 0; i < 4; ++i){
      int tok0 = mt*128 + wr*64 + i*16 + (l >> 4)*4;
      float* dst = Y + (size_t)tok0*1024 + col;
      #pragma unroll
      for (int r = 0; r < 4; ++r) dst[(size_t)r*1024] = acc[i][j][r] + bv;
    }
  }
}

// ---------------- fused sparse attention: 1 WG = (bh, 16 q-rows), 2 blocks/CU ----------------
// Phase 1: u16 exp-keys via mfma(K,Q), K hi/lo direct from global, depth-2 prefetch
// Phase 2: exact 204th-largest key via 16-probe BALLOT bisection (scalar-pipe counting,
//          no shuffle chains); unnormalized exp2 weights -> LDS; zinv per row -> LDS
// Phase 3: PV via mfma(V^T, W) dual-acc, depth-2 prefetch; epilogue scales by zinv
__global__ __launch_bounds__(256) void attn_fused_kernel(
    const float* __restrict__ qbuf, const u16t* __restrict__ khi,
    const u16t* __restrict__ klo, const u16t* __restrict__ vtg,
    u16t* __restrict__ aout)
{
  extern __shared__ char smem[];   // 65536 keys/weights + 64 zinv
  float* zlds = (float*)(smem + 65536);
  const int tid = threadIdx.x;
  const int l = tid & 63, w = tid >> 6;
  int lid = ((blockIdx.x & 7) << 10) | (blockIdx.x >> 3); // XCD-chunked swizzle (8192%8==0)
  const int bh = lid >> 7, qt = lid & 127;
  const int qrow = l & 15;
  const size_t kbase = (size_t)bh*NS*64 + (l >> 4)*8;

  // Phase 0: Q fragments (B operand): row = qrow, d-slice = c*32 + (l>>4)*8
  s16x8 qh[2], ql[2];
  {
    const float* qp = qbuf + ((size_t)bh*NS + qt*16 + qrow)*64 + (l >> 4)*8;
    #pragma unroll
    for (int c = 0; c < 2; ++c){
      float4 va = *(const float4*)(qp + c*32);
      float4 vb = *(const float4*)(qp + c*32 + 4);
      float vv[8] = {va.x,va.y,va.z,va.w,vb.x,vb.y,vb.z,vb.w};
      #pragma unroll
      for (int e = 0; e < 8; ++e){
        u16t hh = f2bf(vv[e]);
        qh[c][e] = (short)hh;
        ql[c][e] = (short)f2bf(vv[e] - bf2f(hh));
      }
    }
  }

  // Phase 1: keys. Wave w handles toks g*64 + w*16 .. +15, g = 0..31; depth-2 prefetch.
  {
    s16x8 Ah0, Ah1, Al0, Al1, Bh0, Bh1, Bl0, Bl1;
    {
      size_t a = kbase + (size_t)(w*16 + qrow)*64;
      Ah0 = *(const s16x8*)(khi + a);  Ah1 = *(const s16x8*)(khi + a + 32);
      Al0 = *(const s16x8*)(klo + a);  Al1 = *(const s16x8*)(klo + a + 32);
      size_t b = kbase + (size_t)(64 + w*16 + qrow)*64;
      Bh0 = *(const s16x8*)(khi + b);  Bh1 = *(const s16x8*)(khi + b + 32);
      Bl0 = *(const s16x8*)(klo + b);  Bl1 = *(const s16x8*)(klo + b + 32);
    }
    for (int g = 0; g < 32; g += 2){
      // even iter: consume A (g), refill A with g+2
      {
        __builtin_amdgcn_s_setprio(1);
        f32x4 aA = {}, aB = {};
        aA = mfma16(Ah0, qh[0], aA);  aB = mfma16(Ah1, qh[1], aB);
        aA = mfma16(Ah0, ql[0], aA);  aB = mfma16(Ah1, ql[1], aB);
        aA = mfma16(Al0, qh[0], aA);  aB = mfma16(Al1, qh[1], aB);
        __builtin_amdgcn_s_setprio(0);
        if (g + 2 < 32){
          size_t a = kbase + (size_t)((g+2)*64 + w*16 + qrow)*64;
          Ah0 = *(const s16x8*)(khi + a);  Ah1 = *(const s16x8*)(khi + a + 32);
          Al0 = *(const s16x8*)(klo + a);  Al1 = *(const s16x8*)(klo + a + 32);
        }
        f32x4 acc = aA + aB;
        int t0 = g*64 + w*16 + (l >> 4)*4;
        u32t k0 = mkkey(acc[0]), k1 = mkkey(acc[1]);
        u32t k2 = mkkey(acc[2]), k3 = mkkey(acc[3]);
        u64t pk = (u64t)(k0 | (k1 << 16)) | ((u64t)(k2 | (k3 << 16)) << 32);
        *(u64t*)(smem + ((qrow*4096 + t0*2) ^ SWZ(qrow))) = pk;
      }
      // odd iter: consume B (g+1), refill B with g+3
      {
        __builtin_amdgcn_s_setprio(1);
        f32x4 aA = {}, aB = {};
        aA = mfma16(Bh0, qh[0], aA);  aB = mfma16(Bh1, qh[1], aB);
        aA = mfma16(Bh0, ql[0], aA);  aB = mfma16(Bh1, ql[1], aB);
        aA = mfma16(Bl0, qh[0], aA);  aB = mfma16(Bl1, qh[1], aB);
        __builtin_amdgcn_s_setprio(0);
        if (g + 3 < 32){
          size_t b = kbase + (size_t)((g+3)*64 + w*16 + qrow)*64;
          Bh0 = *(const s16x8*)(khi + b);  Bh1 = *(const s16x8*)(khi + b + 32);
          Bl0 = *(const s16x8*)(klo + b);  Bl1 = *(const s16x8*)(klo + b + 32);
        }
        f32x4 acc = aA + aB;
        int t0 = (g+1)*64 + w*16 + (l >> 4)*4;
        u32t k0 = mkkey(acc[0]), k1 = mkkey(acc[1]);
        u32t k2 = mkkey(acc[2]), k3 = mkkey(acc[3]);
        u64t pk = (u64t)(k0 | (k1 << 16)) | ((u64t)(k2 | (k3 << 16)) << 32);
        *(u64t*)(smem + ((qrow*4096 + t0*2) ^ SWZ(qrow))) = pk;
      }
    }
  }
  __syncthreads();

  // Phase 2: rows w*4..w*4+3; exact threshold (ballot bisection) + weights + zinv
  for (int rr = 0; rr < 4; ++rr){
    int row = w*4 + rr;
    int rb = row*4096, rs = SWZ(row);
    u32t kk[32];
    #pragma unroll
    for (int i = 0; i < 4; ++i){
      u32x4 v = *(const u32x4*)(smem + ((rb + i*1024 + l*16) ^ rs));
      #pragma unroll
      for (int j = 0; j < 4; ++j){
        kk[(i*4+j)*2]     = v[j] & 0xFFFFu;
        kk[(i*4+j)*2 + 1] = v[j] >> 16;
      }
    }
    // row max (butterfly; independent of the search below -> overlapped)
    u32t km = 0;
    #pragma unroll
    for (int i = 0; i < 32; ++i) km = km > kk[i] ? km : kk[i];
    #pragma unroll
    for (int o = 32; o; o >>= 1){
      u32t t = (u32t)__shfl_xor((int)km, o);
      km = km > t ? km : t;
    }
    // exact 204th-largest key: 16-probe ballot bisection on [0, 65535]
    u32t lo = 0u, hi = 65535u;
    #pragma unroll
    for (int it = 0; it < 16; ++it){
      u32t mid = (lo + hi + 1u) >> 1;
      u32t c = 0;
      #pragma unroll
      for (int i = 0; i < 32; ++i)
        c += (u32t)__popcll(__ballot(kk[i] >= mid));
      if (c >= (u32t)TOPK) lo = mid; else hi = mid - 1u;
    }
    const u32t kbt = lo;

    // weights: kept -> 2^((k-kmx)/1024); masked -> em; UNNORMALIZED; zinv -> LDS
    const u32t kmxe = km < 32768u ? 32768u : km;
    const float dsh = -(float)kmxe * 0.0009765625f;
    const float em = exp2_fast(fmaf(32768.0f, 0.0009765625f, dsh));
    float zs = 0.0f;
    #pragma unroll
    for (int i = 0; i < 4; ++i){
      u32x4 o;
      #pragma unroll
      for (int j = 0; j < 4; ++j){
        int e = (i*4+j)*2;
        float ea = exp2_fast(fmaf((float)kk[e],   0.0009765625f, dsh));
        float eb = exp2_fast(fmaf((float)kk[e+1], 0.0009765625f, dsh));
        float w0 = (kk[e]   >= kbt) ? ea : em;
        float w1 = (kk[e+1] >= kbt) ? eb : em;
        zs += w0 + w1;
        o[j] = pk_bf16(w0, w1);
      }
      *(u32x4*)(smem + ((rb + i*1024 + l*16) ^ rs)) = o;
    }
    #pragma unroll
    for (int o = 32; o; o >>= 1) zs += __shfl_xor(zs, o);
    if (l == 0) zlds[row] = 1.0f / (zs + 1e-9f);
  }
  __syncthreads();

  // Phase 3: PV via mfma(V^T, W): C[d][qrow]. Wave w owns d-block w*16..+15; depth-2 prefetch.
  f32x4 pA = {}, pB = {};
  {
    const u16t* vp = vtg + ((size_t)bh*64 + w*16 + qrow)*NS + (l >> 4)*8;
    s16x8 Va0 = *(const s16x8*)(vp);        s16x8 Va1 = *(const s16x8*)(vp + 32);
    s16x8 Vb0 = *(const s16x8*)(vp + 64);   s16x8 Vb1 = *(const s16x8*)(vp + 96);
    for (int kt = 0; kt < 32; kt += 2){
      {
        int tb = (kt*64 + (l >> 4)*8)*2;
        s16x8 w0 = *(const s16x8*)(smem + ((qrow*4096 + tb) ^ SWZ(qrow)));
        s16x8 w1 = *(const s16x8*)(smem + ((qrow*4096 + tb + 64) ^ SWZ(qrow)));
        __builtin_amdgcn_s_setprio(1);
        pA = mfma16(Va0, w0, pA);
        pB = mfma16(Va1, w1, pB);
        __builtin_amdgcn_s_setprio(0);
        if (kt + 2 < 32){
          Va0 = *(const s16x8*)(vp + (kt+2)*64);
          Va1 = *(const s16x8*)(vp + (kt+2)*64 + 32);
        }
      }
      {
        int tb = ((kt+1)*64 + (l >> 4)*8)*2;
        s16x8 w0 = *(const s16x8*)(smem + ((qrow*4096 + tb) ^ SWZ(qrow)));
        s16x8 w1 = *(const s16x8*)(smem + ((qrow*4096 + tb + 64) ^ SWZ(qrow)));
        __builtin_amdgcn_s_setprio(1);
        pA = mfma16(Vb0, w0, pA);
        pB = mfma16(Vb1, w1, pB);
        __builtin_amdgcn_s_setprio(0);
        if (kt + 3 < 32){
          Vb0 = *(const s16x8*)(vp + (kt+3)*64);
          Vb1 = *(const s16x8*)(vp + (kt+3)*64 + 32);
        }
      }
    }
  }
  f32x4 pacc = pA + pB;
  // epilogue: scale by zinv, store bf16 [B][S][H*64]
  {
    float zi = zlds[qrow];
    int tok = qt*16 + qrow;
    int b = bh >> 4, h = bh & 15;
    int d0 = w*16 + (l >> 4)*4;
    u32t p0 = pk_bf16(pacc[0]*zi, pacc[1]*zi);
    u32t p1 = pk_bf16(pacc[2]*zi, pacc[3]*zi);
    *(u64t*)(aout + ((size_t)(b*NS + tok))*1024 + h*64 + d0) = (u64t)p0 | ((u64t)p1 << 32);
  }
}

// ---------------- workspace layout (132.1 MB, proven available) ----------------
#define O_XHI  ((size_t)0)
#define O_XLO  (O_XHI + (size_t)NTOK*ND*2)
#define O_WQH  (O_XLO + (size_t)NTOK*ND*2)
#define O_WQL  (O_WQH + (size_t)3072*1024*2)
#define O_WOB  (O_WQL + (size_t)3072*1024*2)
#define O_Q    (O_WOB + (size_t)1024*1024*2)
#define O_KHI  (O_Q   + (size_t)NBH*NS*64*4)
#define O_KLO  (O_KHI + (size_t)NBH*NS*64*2)
#define O_VT   (O_KLO + (size_t)NBH*NS*64*2)
#define O_AOUT O_XHI   /* alias: x_hi dead after QKV GEMM */
#define WS_NEED (O_VT + (size_t)NBH*NS*64*2)

#define ATTN_LDS (65536 + 64)

extern "C" void kernel_launch(void* const* d_in, const int* in_sizes, int n_in,
                              void* d_out, int out_size, void* d_ws, size_t ws_size,
                              hipStream_t stream)
{
  (void)in_sizes; (void)n_in; (void)out_size;
  const float* x    = (const float*)d_in[0];
  const float* Wqkv = (const float*)d_in[1];
  const float* bqkv = (const float*)d_in[2];
  const float* Wo   = (const float*)d_in[3];
  const float* bo   = (const float*)d_in[4];
  float* Y = (float*)d_out;
  char* ws = (char*)d_ws;
  if (ws_size < WS_NEED) return;

  u16t* xhi  = (u16t*)(ws + O_XHI);
  u16t* xlo  = (u16t*)(ws + O_XLO);
  u16t* wqh  = (u16t*)(ws + O_WQH);
  u16t* wql  = (u16t*)(ws + O_WQL);
  u16t* wob  = (u16t*)(ws + O_WOB);
  float* qbuf = (float*)(ws + O_Q);
  u16t* khi  = (u16t*)(ws + O_KHI);
  u16t* klo  = (u16t*)(ws + O_KLO);
  u16t* vt   = (u16t*)(ws + O_VT);
  u16t* aout = (u16t*)(ws + O_AOUT);

  hipFuncSetAttribute((const void*)attn_fused_kernel,
                      hipFuncAttributeMaxDynamicSharedMemorySize, ATTN_LDS);

  split_pair_kernel<<<(NTOK*ND/4)/256, 256, 0, stream>>>(x, xhi, xlo, NTOK*ND/4);
  split_pair_kernel<<<(3072*1024/4)/256, 256, 0, stream>>>(Wqkv, wqh, wql, 3072*1024/4);
  cvt_kernel<<<(1024*1024/4)/256, 256, 0, stream>>>(Wo, wob, 1024*1024/4);
  qkv_gemm_kernel<<<dim3(24, 64), 256, 0, stream>>>(xhi, xlo, wqh, wql, bqkv,
                                                    qbuf, khi, klo, vt);
  attn_fused_kernel<<<8192, 256, ATTN_LDS, stream>>>(qbuf, khi, klo, vt, aout);
  out_gemm_kernel<<<dim3(8, 64), 256, 0, stream>>>(aout, wob, bo, Y);
}